// Round 4
// baseline (213.081 us; speedup 1.0000x reference)
//
#include <hip/hip_runtime.h>
#include <hip/hip_bf16.h>

#define NB 16
#define NN 512
#define NH 8
#define NF 128
#define NEG_SLOPE 0.2f

typedef short bf16x8 __attribute__((ext_vector_type(8)));
typedef unsigned short u16x8 __attribute__((ext_vector_type(8)));
typedef float f32x4 __attribute__((ext_vector_type(4)));

__device__ inline unsigned short f2bf(float x) {
    unsigned int u = __float_as_uint(x);
    unsigned int r = (u + 0x7fffu + ((u >> 16) & 1u)) >> 16;   // RNE, finite inputs
    return (unsigned short)r;
}
__device__ inline float bf2f(unsigned short u) {
    return __uint_as_float(((unsigned int)u) << 16);
}

// ---------------- fused prep: mb, h hi/lo split, W^T hi/lo split, wa vectors ----------------
__global__ __launch_bounds__(256) void prep_all_kernel(
    const float* __restrict__ h, const int* __restrict__ adj,
    const float* __restrict__ bias, const float* __restrict__ W,
    const float* __restrict__ a,
    float* __restrict__ mb,
    unsigned short* __restrict__ hHi, unsigned short* __restrict__ hLo,
    unsigned short* __restrict__ wtHi, unsigned short* __restrict__ wtLo,
    float* __restrict__ wasrc, float* __restrict__ wadst)
{
    int t = blockIdx.x * 256 + threadIdx.x;      // grid covers NB*NN*NF = 1048576
    {
        float v = h[t];
        unsigned short hi = f2bf(v);
        hHi[t] = hi;
        hLo[t] = f2bf(v - bf2f(hi));
    }
    if (t < NN * NN) mb[t] = (adj[t] != 0) ? bias[t] : -1.0e30f;
    if (t < NH * NF * NF) {
        int fg = t >> 7, k = t & 127;            // fg = hh*128+f
        float v = W[(size_t)(fg >> 7) * NF * NF + k * NF + (fg & 127)];
        unsigned short hi = f2bf(v);
        wtHi[t] = hi;
        wtLo[t] = f2bf(v - bf2f(hi));
    }
    if (t < NH * NF) {
        int hh = t >> 7, i = t & 127;
        const float* wrow = W + (hh * NF + i) * NF;
        const float* asr = a + hh * 2 * NF;
        const float* ads = asr + NF;
        float s1 = 0.f, s2 = 0.f;
        #pragma unroll 4
        for (int f = 0; f < NF; ++f) {
            float w = wrow[f];
            s1 = fmaf(w, asr[f], s1);
            s2 = fmaf(w, ads[f], s2);
        }
        wasrc[t] = s1; wadst[t] = s2;
    }
}

// ---------------- scores: f32-exact; sdst stored transposed [b][h][n] ----------------
__global__ __launch_bounds__(256) void score_kernel(
    const float* __restrict__ h, const float* __restrict__ wasrc,
    const float* __restrict__ wadst, float* __restrict__ ssrc, float* __restrict__ sdstT)
{
    __shared__ float wsm[2][NH * (NF + 4)];
    int tid = threadIdx.x;
    for (int u = tid; u < NH * NF; u += 256) {
        int hh = u >> 7, f = u & 127;
        wsm[0][hh * (NF + 4) + f] = wasrc[u];
        wsm[1][hh * (NF + 4) + f] = wadst[u];
    }
    __syncthreads();
    int t = blockIdx.x * 256 + tid;           // over B*N*H
    int hh = t & 7;
    int bn = t >> 3;
    int b = bn >> 9, n = bn & 511;
    const float4* hrow = (const float4*)(h + (size_t)bn * NF);
    const float4* w1 = (const float4*)(&wsm[0][hh * (NF + 4)]);
    const float4* w2 = (const float4*)(&wsm[1][hh * (NF + 4)]);
    float s1 = 0.f, s2 = 0.f;
    #pragma unroll
    for (int u = 0; u < NF / 4; ++u) {
        float4 hv = hrow[u], a1 = w1[u], a2 = w2[u];
        s1 += hv.x * a1.x + hv.y * a1.y + hv.z * a1.z + hv.w * a1.w;
        s2 += hv.x * a2.x + hv.y * a2.y + hv.z * a2.z + hv.w * a2.w;
    }
    ssrc[t] = s1;
    sdstT[((size_t)(b * NH + hh)) * NN + n] = s2;
}

// ---------------- h_prime via bf16^3-split MFMA (swapped operands) -> hpT[b][hf][n] ----------------
// A = h rows (n), B = wt rows (f=hh*128+fc). D row = n-local, col = f -> vectorized n-stores.
__global__ __launch_bounds__(256, 4) void hprime_kernel(
    const unsigned short* __restrict__ hHi, const unsigned short* __restrict__ hLo,
    const unsigned short* __restrict__ wtHi, const unsigned short* __restrict__ wtLo,
    unsigned short* __restrict__ hpT)
{
    int tid = threadIdx.x;
    int wave = tid >> 6, lane = tid & 63;
    int col = lane & 15, kg = lane >> 4;
    int n0 = blockIdx.x * 64;                  // global over B*N
    int ftile = blockIdx.y * 4 + wave;         // 0..63
    int fbase = ftile * 16;

    const unsigned short* Bh = wtHi + (size_t)(fbase + col) * NF + kg * 8;
    const unsigned short* Bl = wtLo + (size_t)(fbase + col) * NF + kg * 8;
    const unsigned short* Ah = hHi + (size_t)(n0 + col) * NF + kg * 8;
    const unsigned short* Al = hLo + (size_t)(n0 + col) * NF + kg * 8;

    f32x4 acc[4];
    #pragma unroll
    for (int q = 0; q < 4; ++q) acc[q] = (f32x4){0.f, 0.f, 0.f, 0.f};

    #pragma unroll 2
    for (int ks = 0; ks < 4; ++ks) {
        int off = ks * 32;
        bf16x8 bh = *(const bf16x8*)(Bh + off);
        bf16x8 bl = *(const bf16x8*)(Bl + off);
        #pragma unroll
        for (int q = 0; q < 4; ++q) {
            bf16x8 ah = *(const bf16x8*)(Ah + (size_t)q * 16 * NF + off);
            bf16x8 al = *(const bf16x8*)(Al + (size_t)q * 16 * NF + off);
            acc[q] = __builtin_amdgcn_mfma_f32_16x16x32_bf16(ah, bh, acc[q], 0, 0, 0);
            acc[q] = __builtin_amdgcn_mfma_f32_16x16x32_bf16(al, bh, acc[q], 0, 0, 0);
            acc[q] = __builtin_amdgcn_mfma_f32_16x16x32_bf16(ah, bl, acc[q], 0, 0, 0);
        }
    }

    int b = n0 >> 9;
    int fg = fbase + col;
    size_t rowBase = ((size_t)b * (NH * NF) + fg) * NN;
    #pragma unroll
    for (int q = 0; q < 4; ++q) {
        int n = (n0 & 511) + q * 16 + kg * 4;
        ushort4 u;
        u.x = f2bf(acc[q][0]);
        u.y = f2bf(acc[q][1]);
        u.z = f2bf(acc[q][2]);
        u.w = f2bf(acc[q][3]);
        *(ushort4*)&hpT[rowBase + n] = u;
    }
}

// ---------------- fused attention: shfl-free softmax + MFMA PV + MFMA row-sums ----------------
// grid 1024: blockIdx.x = b*64 + itile*2 + half. 512 threads = 8 waves, 4 blocks/CU.
__global__ __launch_bounds__(512, 8) void attn_kernel(
    const unsigned short* __restrict__ hpT, const float* __restrict__ mb,
    const float* __restrict__ ssrc, const float* __restrict__ sdstT,
    float* __restrict__ out)
{
    __shared__ unsigned short P[16][520];     // 16.6 KB

    int bx = blockIdx.x;
    int half = bx & 1;
    int it = (bx >> 1) & 31;
    int b = bx >> 6;
    int i0 = it * 16;
    int tid = threadIdx.x;
    int lane = tid & 63, wave = tid >> 6;
    int col = lane & 15, kg = lane >> 4;

    const short one_bf = (short)0x3f80;       // bf16 1.0
    const bf16x8 vone = {one_bf, one_bf, one_bf, one_bf, one_bf, one_bf, one_bf, one_bf};

    f32x4 accT = {0.f, 0.f, 0.f, 0.f};

    for (int hq = 0; hq < 4; ++hq) {
        int head = half * 4 + hq;
        const float* sd = sdstT + (size_t)(b * NH + head) * NN;
        // ---- softmax (no max, no cross-lane): rows 2*wave, 2*wave+1; j = lane*8..+7 ----
        #pragma unroll
        for (int rr = 0; rr < 2; ++rr) {
            int i = wave * 2 + rr;
            int row = i0 + i;
            float s_i = ssrc[((size_t)(b * NN + row)) * NH + head];
            const float4* sd4 = (const float4*)(sd + lane * 8);
            const float4* mb4 = (const float4*)(mb + (size_t)row * NN + lane * 8);
            float4 sv0 = sd4[0], sv1 = sd4[1];
            float4 mv0 = mb4[0], mv1 = mb4[1];
            float p[8];
            float x;
            x = s_i + sv0.x; x = x > 0.f ? x : NEG_SLOPE * x; p[0] = __expf(x + mv0.x);
            x = s_i + sv0.y; x = x > 0.f ? x : NEG_SLOPE * x; p[1] = __expf(x + mv0.y);
            x = s_i + sv0.z; x = x > 0.f ? x : NEG_SLOPE * x; p[2] = __expf(x + mv0.z);
            x = s_i + sv0.w; x = x > 0.f ? x : NEG_SLOPE * x; p[3] = __expf(x + mv0.w);
            x = s_i + sv1.x; x = x > 0.f ? x : NEG_SLOPE * x; p[4] = __expf(x + mv1.x);
            x = s_i + sv1.y; x = x > 0.f ? x : NEG_SLOPE * x; p[5] = __expf(x + mv1.y);
            x = s_i + sv1.z; x = x > 0.f ? x : NEG_SLOPE * x; p[6] = __expf(x + mv1.z);
            x = s_i + sv1.w; x = x > 0.f ? x : NEG_SLOPE * x; p[7] = __expf(x + mv1.w);
            u16x8 pw;
            #pragma unroll
            for (int v = 0; v < 8; ++v) pw[v] = f2bf(p[v]);
            *(u16x8*)&P[i][lane * 8] = pw;
        }
        __syncthreads();

        // ---- PV + row-sum MFMAs: wave = f-chunk; C[16 i][16 f], K=512 ----
        const unsigned short* Bp = hpT
            + ((size_t)(b * NH + head) * NF + wave * 16 + col) * NN + kg * 8;
        const unsigned short* Ap = &P[col][kg * 8];
        f32x4 acc0 = {0.f,0.f,0.f,0.f}, acc1 = {0.f,0.f,0.f,0.f};
        f32x4 accS0 = {0.f,0.f,0.f,0.f}, accS1 = {0.f,0.f,0.f,0.f};
        bf16x8 B0v = *(const bf16x8*)(Bp);
        bf16x8 B1v = *(const bf16x8*)(Bp + 32);
        __builtin_amdgcn_s_setprio(1);
        #pragma unroll
        for (int ks = 0; ks < 8; ++ks) {
            bf16x8 a0 = *(const bf16x8*)(Ap + ks * 64);
            bf16x8 a1 = *(const bf16x8*)(Ap + ks * 64 + 32);
            bf16x8 nb0, nb1;
            if (ks < 7) {
                nb0 = *(const bf16x8*)(Bp + ks * 64 + 64);
                nb1 = *(const bf16x8*)(Bp + ks * 64 + 96);
            }
            acc0  = __builtin_amdgcn_mfma_f32_16x16x32_bf16(a0, B0v,  acc0,  0, 0, 0);
            acc1  = __builtin_amdgcn_mfma_f32_16x16x32_bf16(a1, B1v,  acc1,  0, 0, 0);
            accS0 = __builtin_amdgcn_mfma_f32_16x16x32_bf16(a0, vone, accS0, 0, 0, 0);
            accS1 = __builtin_amdgcn_mfma_f32_16x16x32_bf16(a1, vone, accS1, 0, 0, 0);
            if (ks < 7) { B0v = nb0; B1v = nb1; }
        }
        __builtin_amdgcn_s_setprio(0);
        // per-head normalization, fully lane-local (rowsum sits in matching reg slot)
        #pragma unroll
        for (int r = 0; r < 4; ++r)
            accT[r] += (acc0[r] + acc1[r]) / (accS0[r] + accS1[r]);
        __syncthreads();   // before next head overwrites P
    }

    // ---- accumulate the two head-halves via atomics (2 contributors -> deterministic) ----
    #pragma unroll
    for (int r = 0; r < 4; ++r) {
        atomicAdd(&out[((size_t)(b * NN + i0 + kg * 4 + r)) * NF + wave * 16 + col],
                  accT[r] * 0.125f);
    }
}

extern "C" void kernel_launch(void* const* d_in, const int* in_sizes, int n_in,
                              void* d_out, int out_size, void* d_ws, size_t ws_size,
                              hipStream_t stream)
{
    const float* h    = (const float*)d_in[0];
    const int*   adj  = (const int*)d_in[1];
    const float* bias = (const float*)d_in[2];
    const float* W    = (const float*)d_in[3];
    const float* a    = (const float*)d_in[4];
    float* out = (float*)d_out;

    char* ws = (char*)d_ws;
    unsigned short* hpT  = (unsigned short*)ws;   ws += (size_t)NB * NH * NF * NN * 2;   // 16.78 MB
    float* mb    = (float*)ws;                    ws += (size_t)NN * NN * 4;             // 1 MB
    float* ssrc  = (float*)ws;                    ws += (size_t)NB * NN * NH * 4;
    float* sdstT = (float*)ws;                    ws += (size_t)NB * NN * NH * 4;
    float* wasrc = (float*)ws;                    ws += NH * NF * 4;
    float* wadst = (float*)ws;                    ws += NH * NF * 4;
    unsigned short* hHi  = (unsigned short*)ws;   ws += (size_t)NB * NN * NF * 2;        // 2 MB
    unsigned short* hLo  = (unsigned short*)ws;   ws += (size_t)NB * NN * NF * 2;
    unsigned short* wtHi = (unsigned short*)ws;   ws += (size_t)NH * NF * NF * 2;
    unsigned short* wtLo = (unsigned short*)ws;   ws += (size_t)NH * NF * NF * 2;

    hipLaunchKernelGGL(prep_all_kernel, dim3((NB * NN * NF) / 256), dim3(256), 0, stream,
                       h, adj, bias, W, a, mb, hHi, hLo, wtHi, wtLo, wasrc, wadst);
    hipLaunchKernelGGL(score_kernel, dim3((NB * NN * NH) / 256), dim3(256), 0, stream,
                       h, wasrc, wadst, ssrc, sdstT);
    hipLaunchKernelGGL(hprime_kernel, dim3((NB * NN) / 64, (NH * NF) / 64), dim3(256), 0, stream,
                       hHi, hLo, wtHi, wtLo, hpT);
    hipMemsetAsync(d_out, 0, (size_t)out_size * sizeof(float), stream);
    hipLaunchKernelGGL(attn_kernel, dim3(NB * 32 * 2), dim3(512), 0, stream,
                       hpT, mb, ssrc, sdstT, out);
}

// Round 5
// 168.804 us; speedup vs baseline: 1.2623x; 1.2623x over previous
//
#include <hip/hip_runtime.h>
#include <hip/hip_bf16.h>

#define NB 16
#define NN 512
#define NH 8
#define NF 128
#define NEG_SLOPE 0.2f

typedef short bf16x8 __attribute__((ext_vector_type(8)));
typedef unsigned short u16x8 __attribute__((ext_vector_type(8)));
typedef float f32x4 __attribute__((ext_vector_type(4)));

__device__ inline unsigned short f2bf(float x) {
    unsigned int u = __float_as_uint(x);
    unsigned int r = (u + 0x7fffu + ((u >> 16) & 1u)) >> 16;   // RNE, finite inputs
    return (unsigned short)r;
}
__device__ inline float bf2f(unsigned short u) {
    return __uint_as_float(((unsigned int)u) << 16);
}

// ---------------- fused prep: mb, h hi/lo split, W^T hi/lo split, wa vectors ----------------
__global__ __launch_bounds__(256) void prep_all_kernel(
    const float* __restrict__ h, const int* __restrict__ adj,
    const float* __restrict__ bias, const float* __restrict__ W,
    const float* __restrict__ a,
    float* __restrict__ mb,
    unsigned short* __restrict__ hHi, unsigned short* __restrict__ hLo,
    unsigned short* __restrict__ wtHi, unsigned short* __restrict__ wtLo,
    float* __restrict__ wasrc, float* __restrict__ wadst)
{
    int t = blockIdx.x * 256 + threadIdx.x;      // grid covers NB*NN*NF = 1048576
    {
        float v = h[t];
        unsigned short hi = f2bf(v);
        hHi[t] = hi;
        hLo[t] = f2bf(v - bf2f(hi));
    }
    if (t < NN * NN) mb[t] = (adj[t] != 0) ? bias[t] : -1.0e30f;
    if (t < NH * NF * NF) {
        int fg = t >> 7, k = t & 127;            // fg = hh*128+f
        float v = W[(size_t)(fg >> 7) * NF * NF + k * NF + (fg & 127)];
        unsigned short hi = f2bf(v);
        wtHi[t] = hi;
        wtLo[t] = f2bf(v - bf2f(hi));
    }
    if (t < NH * NF) {
        int hh = t >> 7, i = t & 127;
        const float* wrow = W + (hh * NF + i) * NF;
        const float* asr = a + hh * 2 * NF;
        const float* ads = asr + NF;
        float s1 = 0.f, s2 = 0.f;
        #pragma unroll 4
        for (int f = 0; f < NF; ++f) {
            float w = wrow[f];
            s1 = fmaf(w, asr[f], s1);
            s2 = fmaf(w, ads[f], s2);
        }
        wasrc[t] = s1; wadst[t] = s2;
    }
}

// ---------------- scores: f32-exact; sdst stored transposed [b][h][n] ----------------
__global__ __launch_bounds__(256) void score_kernel(
    const float* __restrict__ h, const float* __restrict__ wasrc,
    const float* __restrict__ wadst, float* __restrict__ ssrc, float* __restrict__ sdstT)
{
    __shared__ float wsm[2][NH * (NF + 4)];
    int tid = threadIdx.x;
    for (int u = tid; u < NH * NF; u += 256) {
        int hh = u >> 7, f = u & 127;
        wsm[0][hh * (NF + 4) + f] = wasrc[u];
        wsm[1][hh * (NF + 4) + f] = wadst[u];
    }
    __syncthreads();
    int t = blockIdx.x * 256 + tid;           // over B*N*H
    int hh = t & 7;
    int bn = t >> 3;
    int b = bn >> 9, n = bn & 511;
    const float4* hrow = (const float4*)(h + (size_t)bn * NF);
    const float4* w1 = (const float4*)(&wsm[0][hh * (NF + 4)]);
    const float4* w2 = (const float4*)(&wsm[1][hh * (NF + 4)]);
    float s1 = 0.f, s2 = 0.f;
    #pragma unroll
    for (int u = 0; u < NF / 4; ++u) {
        float4 hv = hrow[u], a1 = w1[u], a2 = w2[u];
        s1 += hv.x * a1.x + hv.y * a1.y + hv.z * a1.z + hv.w * a1.w;
        s2 += hv.x * a2.x + hv.y * a2.y + hv.z * a2.z + hv.w * a2.w;
    }
    ssrc[t] = s1;
    sdstT[((size_t)(b * NH + hh)) * NN + n] = s2;
}

// ---------------- h_prime via bf16^3-split MFMA (swapped operands) -> hpT[b][hf][n] ----------------
__global__ __launch_bounds__(256, 4) void hprime_kernel(
    const unsigned short* __restrict__ hHi, const unsigned short* __restrict__ hLo,
    const unsigned short* __restrict__ wtHi, const unsigned short* __restrict__ wtLo,
    unsigned short* __restrict__ hpT)
{
    int tid = threadIdx.x;
    int wave = tid >> 6, lane = tid & 63;
    int col = lane & 15, kg = lane >> 4;
    int n0 = blockIdx.x * 64;                  // global over B*N
    int ftile = blockIdx.y * 4 + wave;         // 0..63
    int fbase = ftile * 16;

    const unsigned short* Bh = wtHi + (size_t)(fbase + col) * NF + kg * 8;
    const unsigned short* Bl = wtLo + (size_t)(fbase + col) * NF + kg * 8;
    const unsigned short* Ah = hHi + (size_t)(n0 + col) * NF + kg * 8;
    const unsigned short* Al = hLo + (size_t)(n0 + col) * NF + kg * 8;

    f32x4 acc[4];
    #pragma unroll
    for (int q = 0; q < 4; ++q) acc[q] = (f32x4){0.f, 0.f, 0.f, 0.f};

    #pragma unroll 2
    for (int ks = 0; ks < 4; ++ks) {
        int off = ks * 32;
        bf16x8 bh = *(const bf16x8*)(Bh + off);
        bf16x8 bl = *(const bf16x8*)(Bl + off);
        #pragma unroll
        for (int q = 0; q < 4; ++q) {
            bf16x8 ah = *(const bf16x8*)(Ah + (size_t)q * 16 * NF + off);
            bf16x8 al = *(const bf16x8*)(Al + (size_t)q * 16 * NF + off);
            acc[q] = __builtin_amdgcn_mfma_f32_16x16x32_bf16(ah, bh, acc[q], 0, 0, 0);
            acc[q] = __builtin_amdgcn_mfma_f32_16x16x32_bf16(al, bh, acc[q], 0, 0, 0);
            acc[q] = __builtin_amdgcn_mfma_f32_16x16x32_bf16(ah, bl, acc[q], 0, 0, 0);
        }
    }

    int b = n0 >> 9;
    int fg = fbase + col;
    size_t rowBase = ((size_t)b * (NH * NF) + fg) * NN;
    #pragma unroll
    for (int q = 0; q < 4; ++q) {
        int n = (n0 & 511) + q * 16 + kg * 4;
        ushort4 u;
        u.x = f2bf(acc[q][0]);
        u.y = f2bf(acc[q][1]);
        u.z = f2bf(acc[q][2]);
        u.w = f2bf(acc[q][3]);
        *(ushort4*)&hpT[rowBase + n] = u;
    }
}

// ---------------- fused attention: M=32 rows/block, async B-preload, MFMA rowsums ----------------
// grid 512: blockIdx.x = b*32 + it*2 + half. 512 threads = 8 waves. Each wave owns
// C[32 x 16f] as two 16x16 tiles sharing B fragments. part[half] plain stores.
__global__ __launch_bounds__(512) void attn_kernel(
    const unsigned short* __restrict__ hpT, const float* __restrict__ mb,
    const float* __restrict__ ssrc, const float* __restrict__ sdstT,
    float* __restrict__ part)
{
    __shared__ unsigned short P[32][520];     // 33.3 KB -> 2 blocks/CU fit LDS easily

    int bx = blockIdx.x;
    int half = bx & 1;
    int it = (bx >> 1) & 15;
    int b = bx >> 5;
    int i0 = it * 32;
    int tid = threadIdx.x;
    int lane = tid & 63, wave = tid >> 6;     // wave = f-chunk 0..7
    int col = lane & 15, kg = lane >> 4;

    const short one_bf = (short)0x3f80;       // bf16 1.0
    const bf16x8 vone = {one_bf, one_bf, one_bf, one_bf, one_bf, one_bf, one_bf, one_bf};

    f32x4 accT0 = {0.f,0.f,0.f,0.f}, accT1 = {0.f,0.f,0.f,0.f};

    const unsigned short* Ap0 = &P[col][kg * 8];
    const unsigned short* Ap1 = &P[16 + col][kg * 8];

    for (int hq = 0; hq < 4; ++hq) {
        int head = half * 4 + hq;
        const unsigned short* Bp = hpT
            + ((size_t)(b * NH + head) * NF + wave * 16 + col) * NN + kg * 8;

        // ---- stage-1 B preload (latency hides under softmax VALU) ----
        bf16x8 Bv[16];
        #pragma unroll
        for (int ks = 0; ks < 8; ++ks) Bv[ks] = *(const bf16x8*)(Bp + ks * 32);

        // ---- softmax (no max, no cross-lane): rows wave*4..+3; j = lane*8..+7 ----
        const float* sd = sdstT + (size_t)(b * NH + head) * NN;
        #pragma unroll
        for (int rr = 0; rr < 4; ++rr) {
            int i = wave * 4 + rr;
            int row = i0 + i;
            float s_i = ssrc[((size_t)(b * NN + row)) * NH + head];
            const float4* sd4 = (const float4*)(sd + lane * 8);
            const float4* mb4 = (const float4*)(mb + (size_t)row * NN + lane * 8);
            float4 sv0 = sd4[0], sv1 = sd4[1];
            float4 mv0 = mb4[0], mv1 = mb4[1];
            float p[8];
            float x;
            x = s_i + sv0.x; x = x > 0.f ? x : NEG_SLOPE * x; p[0] = __expf(x + mv0.x);
            x = s_i + sv0.y; x = x > 0.f ? x : NEG_SLOPE * x; p[1] = __expf(x + mv0.y);
            x = s_i + sv0.z; x = x > 0.f ? x : NEG_SLOPE * x; p[2] = __expf(x + mv0.z);
            x = s_i + sv0.w; x = x > 0.f ? x : NEG_SLOPE * x; p[3] = __expf(x + mv0.w);
            x = s_i + sv1.x; x = x > 0.f ? x : NEG_SLOPE * x; p[4] = __expf(x + mv1.x);
            x = s_i + sv1.y; x = x > 0.f ? x : NEG_SLOPE * x; p[5] = __expf(x + mv1.y);
            x = s_i + sv1.z; x = x > 0.f ? x : NEG_SLOPE * x; p[6] = __expf(x + mv1.z);
            x = s_i + sv1.w; x = x > 0.f ? x : NEG_SLOPE * x; p[7] = __expf(x + mv1.w);
            u16x8 pw;
            #pragma unroll
            for (int v = 0; v < 8; ++v) pw[v] = f2bf(p[v]);
            *(u16x8*)&P[i][lane * 8] = pw;
        }
        __syncthreads();

        // ---- stage-2 B preload + MFMA: two C tiles share Bv ----
        #pragma unroll
        for (int ks = 8; ks < 16; ++ks) Bv[ks] = *(const bf16x8*)(Bp + ks * 32);

        f32x4 acc0 = {0.f,0.f,0.f,0.f}, accS0 = {0.f,0.f,0.f,0.f};
        f32x4 acc1 = {0.f,0.f,0.f,0.f}, accS1 = {0.f,0.f,0.f,0.f};
        __builtin_amdgcn_s_setprio(1);
        #pragma unroll
        for (int ks = 0; ks < 16; ++ks) {
            bf16x8 a0 = *(const bf16x8*)(Ap0 + ks * 32);
            bf16x8 a1 = *(const bf16x8*)(Ap1 + ks * 32);
            acc0  = __builtin_amdgcn_mfma_f32_16x16x32_bf16(a0, Bv[ks], acc0,  0, 0, 0);
            accS0 = __builtin_amdgcn_mfma_f32_16x16x32_bf16(a0, vone,   accS0, 0, 0, 0);
            acc1  = __builtin_amdgcn_mfma_f32_16x16x32_bf16(a1, Bv[ks], acc1,  0, 0, 0);
            accS1 = __builtin_amdgcn_mfma_f32_16x16x32_bf16(a1, vone,   accS1, 0, 0, 0);
        }
        __builtin_amdgcn_s_setprio(0);
        #pragma unroll
        for (int r = 0; r < 4; ++r) {
            accT0[r] += acc0[r] / accS0[r];
            accT1[r] += acc1[r] / accS1[r];
        }
        __syncthreads();   // all waves done reading P before next head overwrites
    }

    // ---- store partials: rows i0 + {0,16} + kg*4 + r, col f = wave*16 + col ----
    float* po = part + (size_t)half * (NB * NN * NF);
    #pragma unroll
    for (int r = 0; r < 4; ++r) {
        po[((size_t)(b * NN + i0 +  0 + kg * 4 + r)) * NF + wave * 16 + col] = accT0[r];
        po[((size_t)(b * NN + i0 + 16 + kg * 4 + r)) * NF + wave * 16 + col] = accT1[r];
    }
}

// ---------------- combine halves, /8 ----------------
__global__ __launch_bounds__(256) void combine_kernel(
    const float* __restrict__ part, float* __restrict__ out)
{
    int t = blockIdx.x * 256 + threadIdx.x;   // over (B*N*F)/4
    float4 a = ((const float4*)part)[t];
    float4 c = ((const float4*)(part + (size_t)NB * NN * NF))[t];
    float4 o;
    o.x = (a.x + c.x) * 0.125f;
    o.y = (a.y + c.y) * 0.125f;
    o.z = (a.z + c.z) * 0.125f;
    o.w = (a.w + c.w) * 0.125f;
    ((float4*)out)[t] = o;
}

extern "C" void kernel_launch(void* const* d_in, const int* in_sizes, int n_in,
                              void* d_out, int out_size, void* d_ws, size_t ws_size,
                              hipStream_t stream)
{
    const float* h    = (const float*)d_in[0];
    const int*   adj  = (const int*)d_in[1];
    const float* bias = (const float*)d_in[2];
    const float* W    = (const float*)d_in[3];
    const float* a    = (const float*)d_in[4];
    float* out = (float*)d_out;

    char* ws = (char*)d_ws;
    unsigned short* hpT  = (unsigned short*)ws;   ws += (size_t)NB * NH * NF * NN * 2;   // 16.78 MB
    float* mb    = (float*)ws;                    ws += (size_t)NN * NN * 4;             // 1 MB
    float* ssrc  = (float*)ws;                    ws += (size_t)NB * NN * NH * 4;
    float* sdstT = (float*)ws;                    ws += (size_t)NB * NN * NH * 4;
    float* wasrc = (float*)ws;                    ws += NH * NF * 4;
    float* wadst = (float*)ws;                    ws += NH * NF * 4;
    unsigned short* hHi  = (unsigned short*)ws;   ws += (size_t)NB * NN * NF * 2;        // 2 MB
    unsigned short* hLo  = (unsigned short*)ws;   ws += (size_t)NB * NN * NF * 2;
    unsigned short* wtHi = (unsigned short*)ws;   ws += (size_t)NH * NF * NF * 2;
    unsigned short* wtLo = (unsigned short*)ws;   ws += (size_t)NH * NF * NF * 2;
    float* part  = (float*)ws;                    ws += (size_t)2 * NB * NN * NF * 4;    // 8.4 MB

    hipLaunchKernelGGL(prep_all_kernel, dim3((NB * NN * NF) / 256), dim3(256), 0, stream,
                       h, adj, bias, W, a, mb, hHi, hLo, wtHi, wtLo, wasrc, wadst);
    hipLaunchKernelGGL(score_kernel, dim3((NB * NN * NH) / 256), dim3(256), 0, stream,
                       h, wasrc, wadst, ssrc, sdstT);
    hipLaunchKernelGGL(hprime_kernel, dim3((NB * NN) / 64, (NH * NF) / 64), dim3(256), 0, stream,
                       hHi, hLo, wtHi, wtLo, hpT);
    hipLaunchKernelGGL(attn_kernel, dim3(NB * 16 * 2), dim3(512), 0, stream,
                       hpT, mb, ssrc, sdstT, part);
    hipLaunchKernelGGL(combine_kernel, dim3((NB * NN * NF / 4) / 256), dim3(256), 0, stream,
                       part, out);
}